// Round 1
// baseline (25.961 us; speedup 1.0000x reference)
//
#include <hip/hip_runtime.h>
#include <math.h>

// MAM fully-connected: out[r][o] = max_k(x[r][k]*W[o][k]) + min_k(x[r][k]*W[o][k]) + b[o]
// x: (1024, 512) f32, W: (512, 512) f32, b: (512,) f32, out: (1024, 512) f32.
//
// Pure-VALU problem (max/min semiring -> no MFMA). Strategy:
//  - lane = out neuron (64 outs per wave); W chunk held in VGPRs, reused across 8 rows
//  - x loads are wave-uniform -> scalar (SMEM) broadcast loads, zero VALU cost
//  - K split 4-way across the block's 4 waves for occupancy (4 blocks/CU, 4 waves/SIMD)
//  - inner loop shaped so clang emits v_max3_f32 / v_min3_f32 (2 VALU ops per product)

#define O_TOTAL 512
#define K_TOTAL 512
#define OBLK 64          // outs per wave (= lanes)
#define RPB 8            // rows per block
#define NWAVE 4          // waves per block, each owns a K quarter
#define KQ (K_TOTAL / NWAVE)  // 128
#define KCH 32           // K sub-chunk held in VGPRs

__global__ __launch_bounds__(256, 4)
void mam_fc_kernel(const float* __restrict__ x, const float* __restrict__ W,
                   const float* __restrict__ bias, float* __restrict__ out) {
  const int lane = threadIdx.x & 63;
  // readfirstlane makes the wave id provably uniform -> x loads become s_load
  const int wv = __builtin_amdgcn_readfirstlane((int)(threadIdx.x >> 6));
  const int blk = blockIdx.x;
  const int ob = blk & 7;        // 8 out-blocks of 64
  const int rg = blk >> 3;       // 128 row groups of 8
  const int o = ob * OBLK + lane;
  const int row0 = rg * RPB;
  const int k0 = wv * KQ;

  float amax[RPB], amin[RPB];
#pragma unroll
  for (int r = 0; r < RPB; ++r) { amax[r] = -INFINITY; amin[r] = INFINITY; }

  const float* Wo = W + (size_t)o * K_TOTAL + k0;

#pragma unroll
  for (int kc = 0; kc < KQ; kc += KCH) {
    // stage W chunk for this lane's out-neuron into VGPRs (reused across RPB rows)
    float w[KCH];
#pragma unroll
    for (int j = 0; j < KCH; j += 4) {
      const float4 w4 = *reinterpret_cast<const float4*>(Wo + kc + j);
      w[j] = w4.x; w[j + 1] = w4.y; w[j + 2] = w4.z; w[j + 3] = w4.w;
    }
#pragma unroll
    for (int r = 0; r < RPB; ++r) {
      const float* xr = x + (size_t)(row0 + r) * K_TOTAL + k0 + kc;
#pragma unroll
      for (int j = 0; j < KCH; j += 4) {
        const float4 x4 = *reinterpret_cast<const float4*>(xr + j);  // wave-uniform -> s_load
        const float p0 = x4.x * w[j];
        const float p1 = x4.y * w[j + 1];
        const float p2 = x4.z * w[j + 2];
        const float p3 = x4.w * w[j + 3];
        // shaped for v_max3 fusion: max3(p0,p1,p2) then max3(amax,p3,t)
        amax[r] = fmaxf(amax[r], fmaxf(p3, fmaxf(fmaxf(p0, p1), p2)));
        amin[r] = fminf(amin[r], fminf(p3, fminf(fminf(p0, p1), p2)));
      }
    }
  }

  // combine the 4 waves' K-quarter partials via LDS
  __shared__ float redmax[NWAVE][RPB][OBLK];
  __shared__ float redmin[NWAVE][RPB][OBLK];
#pragma unroll
  for (int r = 0; r < RPB; ++r) {
    redmax[wv][r][lane] = amax[r];
    redmin[wv][r][lane] = amin[r];
  }
  __syncthreads();

  const float bv = bias[o];
#pragma unroll
  for (int rr = wv; rr < RPB; rr += NWAVE) {
    float m = redmax[0][rr][lane];
    float n = redmin[0][rr][lane];
#pragma unroll
    for (int q = 1; q < NWAVE; ++q) {
      m = fmaxf(m, redmax[q][rr][lane]);
      n = fminf(n, redmin[q][rr][lane]);
    }
    out[(size_t)(row0 + rr) * O_TOTAL + o] = m + n + bv;
  }
}

extern "C" void kernel_launch(void* const* d_in, const int* in_sizes, int n_in,
                              void* d_out, int out_size, void* d_ws, size_t ws_size,
                              hipStream_t stream) {
  const float* x = (const float*)d_in[0];    // (2*512, 512) flattened
  const float* W = (const float*)d_in[1];    // (512, 512)
  const float* b = (const float*)d_in[2];    // (512,)
  float* out = (float*)d_out;                // (1024, 512)

  const int nrows = in_sizes[0] / K_TOTAL;   // 1024
  const int nblocks = (O_TOTAL / OBLK) * (nrows / RPB);  // 8 * 128 = 1024
  mam_fc_kernel<<<dim3(nblocks), dim3(256), 0, stream>>>(x, W, b, out);
}

// Round 2
// 24.289 us; speedup vs baseline: 1.0688x; 1.0688x over previous
//
#include <hip/hip_runtime.h>
#include <math.h>

// MAM fully-connected: out[r][o] = max_k(x[r][k]*W[o][k]) + min_k(x[r][k]*W[o][k]) + b[o]
// x: (1024, 512) f32, W: (512, 512) f32, b: (512,), out: (1024, 512) f32.
//
// Pure-VALU problem (max/min semiring -> no MFMA). v2 structure:
//  - block = 64 outs x 16 rows, 4 waves each own 4 rows, FULL K per wave (no reduce)
//  - W staged global->LDS in 64x64f chunks, double-buffered: global side fully
//    coalesced (256B/row), LDS side 16B-granule XOR swizzle -> bank-uniform b128
//  - lane = out neuron; w4 read per j-group from LDS, reused across 4 rows
//  - x loads wave-uniform (readfirstlane'd wave id) -> scalarizable broadcast
//  - max chain shaped as 4-deep fmaxf chain -> 2x v_max3 per 4 products
//    (2.0 VALU ops/product -> ~6.8us floor at 78.6 Tops/s f32)

#define O_TOTAL 512
#define K_TOTAL 512
#define OBLK 64
#define NWAVE 4
#define RPW 4                    // rows per wave
#define RPB (NWAVE * RPW)        // 16 rows per block
#define KCH 64                   // K chunk staged in LDS
#define NCHUNK (K_TOTAL / KCH)   // 8

__global__ __launch_bounds__(256, 2)
void mam_fc_kernel(const float* __restrict__ x, const float* __restrict__ W,
                   const float* __restrict__ bias, float* __restrict__ out) {
  __shared__ float Wl[2][OBLK * KCH];   // 2 x 16 KB, XOR-swizzled granules

  const int t = threadIdx.x;
  const int lane = t & 63;
  const int wv = __builtin_amdgcn_readfirstlane(t >> 6);
  const int ob = blockIdx.x & 7;        // 8 out-blocks of 64
  const int rg = blockIdx.x >> 3;       // row groups of 16
  const int o0 = ob * OBLK;
  const int rowBase = rg * RPB + wv * RPW;

  // staging map: thread t covers W rows (t>>4)+16*i, 16B k-granule (t&15)
  const int s_or = t >> 4;              // 0..15
  const int s_g  = t & 15;              // granule index (16B units)

  const float* Wg = W + (size_t)o0 * K_TOTAL;
  const float* xr0 = x + (size_t)rowBase * K_TOTAL;   // wave-uniform base

  float amax[RPW][2], amin[RPW][2];
#pragma unroll
  for (int r = 0; r < RPW; ++r) {
#pragma unroll
    for (int p = 0; p < 2; ++p) { amax[r][p] = -INFINITY; amin[r][p] = INFINITY; }
  }

  // ---- stage chunk 0 into buf 0 ----
#pragma unroll
  for (int i = 0; i < 4; ++i) {
    const int o_l = s_or + 16 * i;
    const float4 v = *reinterpret_cast<const float4*>(Wg + (size_t)o_l * K_TOTAL + s_g * 4);
    const int gsw = s_g ^ (o_l & 15);   // XOR-swizzled 16B granule
    *reinterpret_cast<float4*>(&Wl[0][o_l * KCH + gsw * 4]) = v;
  }
  __syncthreads();

#pragma unroll 1
  for (int c = 0; c < NCHUNK; ++c) {
    // prefetch next chunk into the other buffer (overlaps with compute below)
    if (c + 1 < NCHUNK) {
      const int kc2 = (c + 1) * KCH;
      float* dst = Wl[(c + 1) & 1];
#pragma unroll
      for (int i = 0; i < 4; ++i) {
        const int o_l = s_or + 16 * i;
        const float4 v = *reinterpret_cast<const float4*>(Wg + (size_t)o_l * K_TOTAL + kc2 + s_g * 4);
        const int gsw = s_g ^ (o_l & 15);
        *reinterpret_cast<float4*>(&dst[o_l * KCH + gsw * 4]) = v;
      }
    }

    const float* buf = Wl[c & 1];
    const int kc = c * KCH;
#pragma unroll
    for (int j = 0; j < KCH / 4; ++j) {
      // lane's 4 weights for this j-group (swizzled b128, bank-uniform)
      const float4 w4 = *reinterpret_cast<const float4*>(
          &buf[lane * KCH + ((j ^ (lane & 15)) * 4)]);
      const int par = j & 1;   // split chains by parity -> 16 independent chains
#pragma unroll
      for (int r = 0; r < RPW; ++r) {
        const float4 x4 = *reinterpret_cast<const float4*>(
            xr0 + (size_t)r * K_TOTAL + kc + j * 4);   // wave-uniform
        const float p0 = x4.x * w4.x;
        const float p1 = x4.y * w4.y;
        const float p2 = x4.z * w4.z;
        const float p3 = x4.w * w4.w;
        // pure 4-chain -> v_max3(acc,p0,p1) ; v_max3(t,p2,p3)
        amax[r][par] = fmaxf(fmaxf(fmaxf(fmaxf(amax[r][par], p0), p1), p2), p3);
        amin[r][par] = fminf(fminf(fminf(fminf(amin[r][par], p0), p1), p2), p3);
      }
    }
    __syncthreads();
  }

  const float bv = bias[o0 + lane];
#pragma unroll
  for (int r = 0; r < RPW; ++r) {
    const float m = fmaxf(amax[r][0], amax[r][1]);
    const float n = fminf(amin[r][0], amin[r][1]);
    out[(size_t)(rowBase + r) * O_TOTAL + (o0 + lane)] = m + n + bv;
  }
}

extern "C" void kernel_launch(void* const* d_in, const int* in_sizes, int n_in,
                              void* d_out, int out_size, void* d_ws, size_t ws_size,
                              hipStream_t stream) {
  const float* x = (const float*)d_in[0];    // (1024, 512)
  const float* W = (const float*)d_in[1];    // (512, 512)
  const float* b = (const float*)d_in[2];    // (512,)
  float* out = (float*)d_out;                // (1024, 512)

  const int nrows = in_sizes[0] / K_TOTAL;                 // 1024
  const int nblocks = (O_TOTAL / OBLK) * (nrows / RPB);    // 8 * 64 = 512
  mam_fc_kernel<<<dim3(nblocks), dim3(256), 0, stream>>>(x, W, b, out);
}

// Round 3
// 22.083 us; speedup vs baseline: 1.1756x; 1.0999x over previous
//
#include <hip/hip_runtime.h>
#include <math.h>

// MAM fully-connected: out[r][o] = max_k(x[r][k]*W[o][k]) + min_k(x[r][k]*W[o][k]) + b[o]
// x: (1024, 512) f32, W: (512, 512) f32, b: (512,), out: (1024, 512) f32.
//
// v3: pure-VALU problem (no MFMA for max/min semiring). Structure:
//  - 1024 blocks (64 outs x 8 rows) -> 4 blocks/CU, 4 waves/SIMD (latency hiding)
//  - W: global->LDS via global_load_lds width-16, source pre-swizzled
//    (phys granule p of row o holds logical group p^(o&15)) so the LDS dest is
//    linear (HW requires base+lane*16) and in-loop reads are bank-uniform b128
//  - x: staged to LDS linear; inner-loop x reads are uniform-address ds_read_b128
//    (HW broadcast, conflict-free, immediate offsets, zero addressing VALU)
//  - inner loop: per j = 1 w-read (1 v_xor addr) + 2 x-reads + 16 VALU
//    (4-deep fmax/fmin chains -> v_max3/v_min3, 2 ops/product, ~6.8us floor)

#define O_TOTAL 512
#define K_TOTAL 512
#define OBLK 64
#define NWAVE 4
#define RPW 2                    // rows per wave
#define RPB (NWAVE * RPW)        // 8 rows per block
#define KCH 64                   // K chunk staged in LDS
#define NCHUNK (K_TOTAL / KCH)   // 8

__device__ __forceinline__ void stage16(const float* g, float* lds, int lane) {
#if __has_builtin(__builtin_amdgcn_global_load_lds)
  (void)lane;
  __builtin_amdgcn_global_load_lds(
      (__attribute__((address_space(1))) unsigned int*)g,
      (__attribute__((address_space(3))) unsigned int*)lds, 16, 0, 0);
#else
  *reinterpret_cast<float4*>(lds + lane * 4) = *reinterpret_cast<const float4*>(g);
#endif
}

__global__ __launch_bounds__(256, 4)
void mam_fc_kernel(const float* __restrict__ x, const float* __restrict__ W,
                   const float* __restrict__ bias, float* __restrict__ out) {
  __shared__ float Wl[2][OBLK * KCH];   // 2 x 16 KB, phys granule p = logical ^ (o&15)
  __shared__ float Xl[2][RPB * KCH];    // 2 x 2 KB, linear

  const int t = threadIdx.x;
  const int lane = t & 63;
  const int wv = __builtin_amdgcn_readfirstlane(t >> 6);
  const int ob = blockIdx.x & 7;        // 8 out-blocks of 64
  const int rg = blockIdx.x >> 3;       // 128 row-groups of 8
  const int o0 = ob * OBLK;
  const int rowBase = rg * RPB;

  // ---- W staging plan: wave wv covers rows [wv*16, wv*16+16), 4 passes of 4 rows ----
  // pass p: lane covers row orow = wv*16 + p*4 + (lane>>4), phys granule lane&15;
  // source granule = (lane&15) ^ (orow&15)  (pre-swizzled global address, linear LDS dest)
  const float* srcW[4];
  int dstWoff[4];
#pragma unroll
  for (int p = 0; p < 4; ++p) {
    const int orow = wv * 16 + p * 4 + (lane >> 4);
    const int g = (lane & 15) ^ (orow & 15);
    srcW[p] = W + (size_t)(o0 + orow) * K_TOTAL + g * 4;
    dstWoff[p] = (wv * 16 + p * 4) * KCH;   // wave-uniform float offset
  }
  // ---- x staging plan: waves 0,1 cover rows wv*4 + (lane>>4), granule lane&15, linear ----
  const float* srcX = x + (size_t)(rowBase + wv * 4 + (lane >> 4)) * K_TOTAL + (lane & 15) * 4;
  const int dstXoff = wv * 4 * KCH;

  float amax[RPW][2], amin[RPW][2];
#pragma unroll
  for (int r = 0; r < RPW; ++r) {
#pragma unroll
    for (int p = 0; p < 2; ++p) { amax[r][p] = -INFINITY; amin[r][p] = INFINITY; }
  }

  const unsigned baseW = (unsigned)(lane * (KCH * 4) + (lane & 15) * 16);  // byte offset
  const unsigned baseX = (unsigned)((wv * RPW) * (KCH * 4));               // byte offset

  // prologue: stage chunk 0 into buf 0
#pragma unroll
  for (int p = 0; p < 4; ++p) stage16(srcW[p], &Wl[0][dstWoff[p]], lane);
  if (wv < 2) stage16(srcX, &Xl[0][dstXoff], lane);
  __syncthreads();

#pragma unroll 1
  for (int c = 0; c < NCHUNK; ++c) {
    // prefetch chunk c+1 into the other buffer (completes at the trailing barrier)
    if (c + 1 < NCHUNK) {
      const int b = (c + 1) & 1;
      const int kOff = (c + 1) * KCH;
#pragma unroll
      for (int p = 0; p < 4; ++p) stage16(srcW[p] + kOff, &Wl[b][dstWoff[p]], lane);
      if (wv < 2) stage16(srcX + kOff, &Xl[b][dstXoff], lane);
    }

    const char* wb = (const char*)&Wl[c & 1][0];
    const char* xb = (const char*)&Xl[c & 1][0];
#pragma unroll
    for (int j = 0; j < KCH / 4; ++j) {
      // lane's logical k-group j sits at phys granule j^(lane&15); bit-disjoint -> one v_xor
      const float4 w4 = *reinterpret_cast<const float4*>(wb + (baseW ^ (unsigned)(j * 16)));
#pragma unroll
      for (int r = 0; r < RPW; ++r) {
        // uniform address -> LDS broadcast, immediate offset
        const float4 x4 = *reinterpret_cast<const float4*>(xb + baseX + r * (KCH * 4) + j * 16);
        const float p0 = x4.x * w4.x;
        const float p1 = x4.y * w4.y;
        const float p2 = x4.z * w4.z;
        const float p3 = x4.w * w4.w;
        const int par = j & 1;  // parity-split chains for ILP
        amax[r][par] = fmaxf(fmaxf(fmaxf(fmaxf(amax[r][par], p0), p1), p2), p3);
        amin[r][par] = fminf(fminf(fminf(fminf(amin[r][par], p0), p1), p2), p3);
      }
    }
    __syncthreads();   // compiler emits vmcnt(0) drain -> next buffer ready
  }

  const float bv = bias[o0 + lane];
#pragma unroll
  for (int r = 0; r < RPW; ++r) {
    const float mm = fmaxf(amax[r][0], amax[r][1]);
    const float nn = fminf(amin[r][0], amin[r][1]);
    out[(size_t)(rowBase + wv * RPW + r) * O_TOTAL + o0 + lane] = mm + nn + bv;
  }
}

extern "C" void kernel_launch(void* const* d_in, const int* in_sizes, int n_in,
                              void* d_out, int out_size, void* d_ws, size_t ws_size,
                              hipStream_t stream) {
  const float* x = (const float*)d_in[0];    // (1024, 512)
  const float* W = (const float*)d_in[1];    // (512, 512)
  const float* b = (const float*)d_in[2];    // (512,)
  float* out = (float*)d_out;                // (1024, 512)

  const int nrows = in_sizes[0] / K_TOTAL;                 // 1024
  const int nblocks = (O_TOTAL / OBLK) * (nrows / RPB);    // 8 * 128 = 1024
  mam_fc_kernel<<<dim3(nblocks), dim3(256), 0, stream>>>(x, W, b, out);
}